// Round 1
// baseline (1712.268 us; speedup 1.0000x reference)
//
#include <hip/hip_runtime.h>
#include <hip/hip_bf16.h>

#define HW 16384
#define NCH 128
#define SCALE 0.17677669529663687f  // 1/sqrt(32)

// ---------------------------------------------------------------------------
// K1/K5: Y[o][p] = sum_c W[o][c] * X[c][p] (+ bias[o])   K=128 fixed
// grid (M/64, HW/128), block 256
// ---------------------------------------------------------------------------
__global__ __launch_bounds__(256) void gemm_ox(
    const float* __restrict__ W, const float* __restrict__ X,
    const float* __restrict__ bias, float* __restrict__ Y) {
  __shared__ float w_s[64][128];
  __shared__ float x_s[16][128];
  const int o0 = blockIdx.x * 64;
  const int p0 = blockIdx.y * 128;
  const int t = threadIdx.x;

  #pragma unroll
  for (int i = 0; i < 32; ++i) {
    int idx = t + i * 256;           // 8192 elements
    int o = idx >> 7, c = idx & 127;
    w_s[o][c] = W[(o0 + o) * 128 + c];
  }

  float acc[8][4] = {};
  const int pt = t & 31, ot = t >> 5;   // 32 p-threads x 8 o-threads

  for (int c0 = 0; c0 < 128; c0 += 16) {
    __syncthreads();
    #pragma unroll
    for (int i = 0; i < 8; ++i) {
      int idx = t + i * 256;         // 2048 elements
      int cc = idx >> 7, p = idx & 127;
      x_s[cc][p] = X[(c0 + cc) * HW + p0 + p];
    }
    __syncthreads();
    #pragma unroll
    for (int cc = 0; cc < 16; ++cc) {
      float4 xv = *(const float4*)&x_s[cc][pt * 4];
      #pragma unroll
      for (int oo = 0; oo < 8; ++oo) {
        float wv = w_s[ot * 8 + oo][c0 + cc];
        acc[oo][0] += wv * xv.x; acc[oo][1] += wv * xv.y;
        acc[oo][2] += wv * xv.z; acc[oo][3] += wv * xv.w;
      }
    }
  }
  #pragma unroll
  for (int oo = 0; oo < 8; ++oo) {
    int o = o0 + ot * 8 + oo;
    float b = bias ? bias[o] : 0.f;
    float4 r = {acc[oo][0] + b, acc[oo][1] + b, acc[oo][2] + b, acc[oo][3] + b};
    *(float4*)&Y[o * HW + p0 + pt * 4] = r;
  }
}

// ---------------------------------------------------------------------------
// K2: pass A — Z_c = sum_e exp(scale * q_c . k_e); store 1/Z
// grid (32 = bh*8+n, 8 c-chunks of 256), block 256, thread owns row c
// ---------------------------------------------------------------------------
__global__ __launch_bounds__(256) void attn_stats(
    const float* __restrict__ qkv, float* __restrict__ zinv) {
  const int bn = blockIdx.x;
  const int bh = bn >> 3, n = bn & 7;
  const int c = blockIdx.y * 256 + threadIdx.x;
  const float* qb = qkv + (bh * 32) * HW + n * 2048;
  const float* kb = qkv + (128 + bh * 32) * HW + n * 2048;

  float q[32];
  #pragma unroll
  for (int d = 0; d < 32; ++d) q[d] = qb[d * HW + c] * SCALE;

  __shared__ float k_s[64][36];
  float Z = 0.f;
  for (int e0 = 0; e0 < 2048; e0 += 64) {
    __syncthreads();
    #pragma unroll
    for (int i = 0; i < 8; ++i) {
      int idx = threadIdx.x + i * 256;  // 2048
      int d = idx >> 6, e = idx & 63;
      k_s[e][d] = kb[d * HW + e0 + e];
    }
    __syncthreads();
    #pragma unroll 4
    for (int e = 0; e < 64; ++e) {
      float s0 = 0, s1 = 0, s2 = 0, s3 = 0;
      const float4* kc = (const float4*)&k_s[e][0];
      #pragma unroll
      for (int dd = 0; dd < 8; ++dd) {
        float4 kv = kc[dd];
        s0 += q[dd * 4 + 0] * kv.x; s1 += q[dd * 4 + 1] * kv.y;
        s2 += q[dd * 4 + 2] * kv.z; s3 += q[dd * 4 + 3] * kv.w;
      }
      Z += __expf((s0 + s1) + (s2 + s3));
    }
  }
  zinv[bn * 2048 + c] = 1.f / Z;
}

// ---------------------------------------------------------------------------
// K3: pass B — out[d,j] = sum_c (v[d,c]/Z_c) * exp(scale * q_c . k_j)
// grid (32, 8 j-chunks of 256), block 256, thread owns column j (32 accs)
// ---------------------------------------------------------------------------
__global__ __launch_bounds__(256) void attn_apply(
    const float* __restrict__ qkv, const float* __restrict__ zinv,
    float* __restrict__ out) {
  const int bn = blockIdx.x;
  const int bh = bn >> 3, n = bn & 7;
  const int j = blockIdx.y * 256 + threadIdx.x;
  const float* qb = qkv + (bh * 32) * HW + n * 2048;
  const float* kb = qkv + (128 + bh * 32) * HW + n * 2048;
  const float* vb = qkv + (256 + bh * 32) * HW + n * 2048;

  float kj[32];
  #pragma unroll
  for (int d = 0; d < 32; ++d) kj[d] = kb[d * HW + j];

  float acc[32] = {};
  __shared__ float q_s[64][36];
  __shared__ float v_s[64][36];

  for (int c0 = 0; c0 < 2048; c0 += 64) {
    __syncthreads();
    #pragma unroll
    for (int i = 0; i < 8; ++i) {
      int idx = threadIdx.x + i * 256;
      int d = idx >> 6, cc = idx & 63;
      q_s[cc][d] = qb[d * HW + c0 + cc] * SCALE;
      v_s[cc][d] = vb[d * HW + c0 + cc] * zinv[bn * 2048 + c0 + cc];
    }
    __syncthreads();
    #pragma unroll 2
    for (int cc = 0; cc < 64; ++cc) {
      float s0 = 0, s1 = 0, s2 = 0, s3 = 0;
      const float4* qc = (const float4*)&q_s[cc][0];
      #pragma unroll
      for (int dd = 0; dd < 8; ++dd) {
        float4 qv = qc[dd];
        s0 += kj[dd * 4 + 0] * qv.x; s1 += kj[dd * 4 + 1] * qv.y;
        s2 += kj[dd * 4 + 2] * qv.z; s3 += kj[dd * 4 + 3] * qv.w;
      }
      float p = __expf((s0 + s1) + (s2 + s3));
      const float4* vc = (const float4*)&v_s[cc][0];
      #pragma unroll
      for (int dd = 0; dd < 8; ++dd) {
        float4 vv = vc[dd];
        acc[dd * 4 + 0] += p * vv.x; acc[dd * 4 + 1] += p * vv.y;
        acc[dd * 4 + 2] += p * vv.z; acc[dd * 4 + 3] += p * vv.w;
      }
    }
  }
  #pragma unroll
  for (int d = 0; d < 32; ++d) out[(bh * 32 + d) * HW + n * 2048 + j] = acc[d];
}

// ---------------------------------------------------------------------------
// K4a: per-channel mean of attn_out -> s[128]
// ---------------------------------------------------------------------------
__global__ __launch_bounds__(256) void row_mean(
    const float* __restrict__ out, float* __restrict__ s) {
  const int ch = blockIdx.x;
  float sum = 0;
  const float4* row = (const float4*)(out + ch * HW);
  for (int p = threadIdx.x; p < HW / 4; p += 256) {
    float4 v = row[p];
    sum += (v.x + v.y) + (v.z + v.w);
  }
  __shared__ float red[256];
  red[threadIdx.x] = sum;
  __syncthreads();
  for (int st = 128; st > 0; st >>= 1) {
    if (threadIdx.x < st) red[threadIdx.x] += red[threadIdx.x + st];
    __syncthreads();
  }
  if (threadIdx.x == 0) s[ch] = red[0] * (1.f / HW);
}

// ---------------------------------------------------------------------------
// K4b: SE MLP -> gate g, and w_g[o][c] = out_w[o][c] * g[c]   (1 block, 128 thr)
// ---------------------------------------------------------------------------
__global__ __launch_bounds__(128) void se_mlp(
    const float* __restrict__ s, const float* __restrict__ w1,
    const float* __restrict__ b1, const float* __restrict__ w2,
    const float* __restrict__ b2, const float* __restrict__ out_w,
    float* __restrict__ w_g) {
  __shared__ float s_sh[128], s1_sh[32], g_sh[128];
  const int t = threadIdx.x;
  s_sh[t] = s[t];
  __syncthreads();
  if (t < 32) {
    float a = b1[t];
    for (int c = 0; c < 128; ++c) a += w1[t * 128 + c] * s_sh[c];
    s1_sh[t] = a / (1.f + __expf(-a));  // silu
  }
  __syncthreads();
  {
    float a = b2[t];
    for (int i = 0; i < 32; ++i) a += w2[t * 32 + i] * s1_sh[i];
    g_sh[t] = 1.f / (1.f + __expf(-a));  // sigmoid
  }
  __syncthreads();
  for (int o = 0; o < 128; ++o) w_g[o * 128 + t] = out_w[o * 128 + t] * g_sh[t];
}

// ---------------------------------------------------------------------------
// K6: GroupNorm partial sums.  grid (8 groups, 32 chunks), block 256
// ---------------------------------------------------------------------------
__global__ __launch_bounds__(256) void gn_partial(
    const float* __restrict__ y, float* __restrict__ part) {
  const int g = blockIdx.x, bk = blockIdx.y;
  float s = 0, ss = 0;
  const float4* base = (const float4*)(y + g * 16 * HW + bk * 8192);
  for (int i = threadIdx.x; i < 2048; i += 256) {
    float4 v = base[i];
    s += (v.x + v.y) + (v.z + v.w);
    ss += (v.x * v.x + v.y * v.y) + (v.z * v.z + v.w * v.w);
  }
  __shared__ float r1[256], r2[256];
  r1[threadIdx.x] = s; r2[threadIdx.x] = ss;
  __syncthreads();
  for (int st = 128; st > 0; st >>= 1) {
    if (threadIdx.x < st) {
      r1[threadIdx.x] += r1[threadIdx.x + st];
      r2[threadIdx.x] += r2[threadIdx.x + st];
    }
    __syncthreads();
  }
  if (threadIdx.x == 0) {
    part[(g * 32 + bk) * 2 + 0] = r1[0];
    part[(g * 32 + bk) * 2 + 1] = r2[0];
  }
}

// K7: finalize stats (1 block)
__global__ void gn_finalize(const float* __restrict__ part, float* __restrict__ stat) {
  const int g = threadIdx.x;
  if (g >= 8) return;
  float s = 0, ss = 0;
  for (int i = 0; i < 32; ++i) {
    s += part[(g * 32 + i) * 2 + 0];
    ss += part[(g * 32 + i) * 2 + 1];
  }
  const float inv_n = 1.f / (16.f * HW);
  float mu = s * inv_n;
  float var = ss * inv_n - mu * mu;
  stat[g * 2 + 0] = mu;
  stat[g * 2 + 1] = rsqrtf(var + 1e-5f);
}

// K8: apply GN affine -> d_out
__global__ __launch_bounds__(256) void gn_apply(
    const float* __restrict__ y, const float* __restrict__ stat,
    const float* __restrict__ gn_w, const float* __restrict__ gn_b,
    float* __restrict__ outp) {
  const int i = (blockIdx.x * 256 + threadIdx.x) * 4;
  const int ch = i >> 14;          // /HW
  const int g = ch >> 4;
  float mu = stat[g * 2], rs = stat[g * 2 + 1];
  float w = gn_w[ch] * rs;
  float b = gn_b[ch] - mu * w;
  float4 v = *(const float4*)&y[i];
  float4 r = {v.x * w + b, v.y * w + b, v.z * w + b, v.w * w + b};
  *(float4*)&outp[i] = r;
}

// ---------------------------------------------------------------------------
extern "C" void kernel_launch(void* const* d_in, const int* in_sizes, int n_in,
                              void* d_out, int out_size, void* d_ws, size_t ws_size,
                              hipStream_t stream) {
  const float* x     = (const float*)d_in[0];
  const float* w_qkv = (const float*)d_in[1];
  const float* se_w1 = (const float*)d_in[2];
  const float* se_b1 = (const float*)d_in[3];
  const float* se_w2 = (const float*)d_in[4];
  const float* se_b2 = (const float*)d_in[5];
  const float* out_w = (const float*)d_in[6];
  const float* out_b = (const float*)d_in[7];
  const float* gn_w  = (const float*)d_in[8];
  const float* gn_b  = (const float*)d_in[9];
  float* out = (float*)d_out;

  float* ws = (float*)d_ws;
  float* qkv      = ws;                       // 384*16384 = 6291456
  float* zinv     = qkv + 6291456;            // 65536
  float* attn_out = zinv + 65536;             // 2097152
  float* se_s     = attn_out + 2097152;       // 128
  float* w_g      = se_s + 128;               // 16384
  float* ybuf     = w_g + 16384;              // 2097152
  float* part     = ybuf + 2097152;           // 512
  float* stat     = part + 512;               // 16

  // K1: qkv = w_qkv @ x
  gemm_ox<<<dim3(6, 128), 256, 0, stream>>>(w_qkv, x, nullptr, qkv);
  // K2: softmax denominators
  attn_stats<<<dim3(32, 8), 256, 0, stream>>>(qkv, zinv);
  // K3: attention output
  attn_apply<<<dim3(32, 8), 256, 0, stream>>>(qkv, zinv, attn_out);
  // K4: SE path
  row_mean<<<128, 256, 0, stream>>>(attn_out, se_s);
  se_mlp<<<1, 128, 0, stream>>>(se_s, se_w1, se_b1, se_w2, se_b2, out_w, w_g);
  // K5: y = w_g @ attn_out + out_b
  gemm_ox<<<dim3(2, 128), 256, 0, stream>>>(w_g, attn_out, out_b, ybuf);
  // K6-K8: GroupNorm
  gn_partial<<<dim3(8, 32), 256, 0, stream>>>(ybuf, part);
  gn_finalize<<<1, 64, 0, stream>>>(part, stat);
  gn_apply<<<2048, 256, 0, stream>>>(ybuf, stat, gn_w, gn_b, out);
}

// Round 2
// 154.622 us; speedup vs baseline: 11.0739x; 11.0739x over previous
//
#include <hip/hip_runtime.h>
#include <hip/hip_bf16.h>

#define HW 16384
#define SCALE 0.17677669529663687f  // 1/sqrt(32)

typedef __attribute__((ext_vector_type(8))) short short8;
typedef __attribute__((ext_vector_type(4))) float floatx4;

__device__ inline unsigned pack_bf16_2(float a, float b) {
  union { __hip_bfloat162 h; unsigned u; } c;
  c.h = __float22bfloat162_rn(make_float2(a, b));
  return c.u;
}

// ---------------------------------------------------------------------------
// K1/K5: Y[o][p] = sum_c W[o][c] * X[c][p] (+ bias[o])   K=128 fixed, fp32
// ---------------------------------------------------------------------------
__global__ __launch_bounds__(256) void gemm_ox(
    const float* __restrict__ W, const float* __restrict__ X,
    const float* __restrict__ bias, float* __restrict__ Y) {
  __shared__ float w_s[64][128];
  __shared__ float x_s[16][128];
  const int o0 = blockIdx.x * 64;
  const int p0 = blockIdx.y * 128;
  const int t = threadIdx.x;

  #pragma unroll
  for (int i = 0; i < 32; ++i) {
    int idx = t + i * 256;
    int o = idx >> 7, c = idx & 127;
    w_s[o][c] = W[(o0 + o) * 128 + c];
  }

  float acc[8][4] = {};
  const int pt = t & 31, ot = t >> 5;

  for (int c0 = 0; c0 < 128; c0 += 16) {
    __syncthreads();
    #pragma unroll
    for (int i = 0; i < 8; ++i) {
      int idx = t + i * 256;
      int cc = idx >> 7, p = idx & 127;
      x_s[cc][p] = X[(c0 + cc) * HW + p0 + p];
    }
    __syncthreads();
    #pragma unroll
    for (int cc = 0; cc < 16; ++cc) {
      float4 xv = *(const float4*)&x_s[cc][pt * 4];
      #pragma unroll
      for (int oo = 0; oo < 8; ++oo) {
        float wv = w_s[ot * 8 + oo][c0 + cc];
        acc[oo][0] += wv * xv.x; acc[oo][1] += wv * xv.y;
        acc[oo][2] += wv * xv.z; acc[oo][3] += wv * xv.w;
      }
    }
  }
  #pragma unroll
  for (int oo = 0; oo < 8; ++oo) {
    int o = o0 + ot * 8 + oo;
    float b = bias ? bias[o] : 0.f;
    float4 r = {acc[oo][0] + b, acc[oo][1] + b, acc[oo][2] + b, acc[oo][3] + b};
    *(float4*)&Y[o * HW + p0 + pt * 4] = r;
  }
}

// ---------------------------------------------------------------------------
// transpose_qk: qkv fp32 [d][hw] -> q_t/k_t bf16 [bn][c 2048][d 32]
// q gets SCALE folded in. grid (8 c-tiles, 32 bn, 2 qk), block 256
// ---------------------------------------------------------------------------
__global__ __launch_bounds__(256) void transpose_qk(
    const float* __restrict__ qkv, unsigned short* __restrict__ q_t,
    unsigned short* __restrict__ k_t) {
  __shared__ float tile[32][257];
  const int qk = blockIdx.z, bn = blockIdx.y, c0 = blockIdx.x * 256;
  const int bh = bn >> 3, nn = bn & 7;
  const int t = threadIdx.x;
  const float* src = qkv + (qk * 128 + bh * 32) * HW + nn * 2048 + c0;
  #pragma unroll
  for (int d = 0; d < 32; ++d) tile[d][t] = src[d * HW + t];
  __syncthreads();
  const float sc = qk ? 1.f : SCALE;
  unsigned short* dst = (qk ? k_t : q_t) + (bn * 2048 + c0 + t) * 32;
  unsigned u[16];
  #pragma unroll
  for (int i = 0; i < 16; ++i)
    u[i] = pack_bf16_2(tile[2 * i][t] * sc, tile[2 * i + 1][t] * sc);
  #pragma unroll
  for (int i = 0; i < 4; ++i) *(uint4*)&dst[i * 8] = *(const uint4*)&u[i * 4];
}

// ---------------------------------------------------------------------------
// Pass A: Z_c = sum_e exp(q_c . k_e * scale); store 1/Z.
// grid (8, 32), block 512. Wave owns 32 c-rows (2 M-tiles), loops e.
// ---------------------------------------------------------------------------
__global__ __launch_bounds__(512) void attn_stats_mfma(
    const unsigned short* __restrict__ q_t, const unsigned short* __restrict__ k_t,
    float* __restrict__ zinv) {
  const int wave = threadIdx.x >> 6, lane = threadIdx.x & 63;
  const int bn = blockIdx.y;
  const int c0 = blockIdx.x * 256 + wave * 32;
  const int lr = lane & 15, lk = (lane >> 4) * 8;

  short8 aq0 = *(const short8*)&q_t[(bn * 2048 + c0 + lr) * 32 + lk];
  short8 aq1 = *(const short8*)&q_t[(bn * 2048 + c0 + 16 + lr) * 32 + lk];
  float z[2][4] = {};
  const unsigned short* kb = &k_t[bn * 2048 * 32];
  const floatx4 zero = {0.f, 0.f, 0.f, 0.f};

  for (int e0 = 0; e0 < 2048; e0 += 16) {
    short8 bk = *(const short8*)&kb[(e0 + lr) * 32 + lk];
    floatx4 s0 = __builtin_amdgcn_mfma_f32_16x16x32_bf16(aq0, bk, zero, 0, 0, 0);
    floatx4 s1 = __builtin_amdgcn_mfma_f32_16x16x32_bf16(aq1, bk, zero, 0, 0, 0);
    #pragma unroll
    for (int r = 0; r < 4; ++r) {
      z[0][r] += __expf(s0[r]);
      z[1][r] += __expf(s1[r]);
    }
  }
  #pragma unroll
  for (int mt = 0; mt < 2; ++mt) {
    #pragma unroll
    for (int r = 0; r < 4; ++r) {
      float v = z[mt][r];
      v += __shfl_xor(v, 1); v += __shfl_xor(v, 2);
      v += __shfl_xor(v, 4); v += __shfl_xor(v, 8);
      if (lr == 0)
        zinv[bn * 2048 + c0 + mt * 16 + (lane >> 4) * 4 + r] = 1.f / v;
    }
  }
}

// ---------------------------------------------------------------------------
// vz = v * zinv[c], cast to bf16, natural [d][hw] layout. grid 2048, block 256
// ---------------------------------------------------------------------------
__global__ __launch_bounds__(256) void vz_cast(
    const float* __restrict__ qkv, const float* __restrict__ zinv,
    unsigned short* __restrict__ vz) {
  const int idx = (blockIdx.x * 256 + threadIdx.x) * 4;
  const int row = idx >> 14, p = idx & 16383;
  const int bh = row >> 5, nn = p >> 11, c = p & 2047;
  float4 v = *(const float4*)&qkv[(256 + row) * HW + p];
  float4 zi = *(const float4*)&zinv[(bh * 8 + nn) * 2048 + c];
  unsigned u0 = pack_bf16_2(v.x * zi.x, v.y * zi.y);
  unsigned u1 = pack_bf16_2(v.z * zi.z, v.w * zi.w);
  uint2 o = {u0, u1};
  *(uint2*)&vz[row * HW + p] = o;
}

// ---------------------------------------------------------------------------
// Pass B: out[d,j] = sum_c vz[d,c] * exp(S[c,j]).
// grid (8 j-tiles, 32 bn), block 512. Wave owns 32 j cols, loops c in 32s.
// Per-wave private P^T tile in LDS bridges QK C-layout -> PV B-layout.
// ---------------------------------------------------------------------------
__global__ __launch_bounds__(512) void attn_apply_mfma(
    const unsigned short* __restrict__ q_t, const unsigned short* __restrict__ k_t,
    const unsigned short* __restrict__ vz, float* __restrict__ attn_out) {
  __shared__ unsigned short pt[8][32][32];  // [wave][j][c] = P^T
  const int wave = threadIdx.x >> 6, lane = threadIdx.x & 63;
  const int bn = blockIdx.y, bh = bn >> 3, nn = bn & 7;
  const int j0 = blockIdx.x * 256 + wave * 32;
  const int lr = lane & 15, lk = (lane >> 4) * 8;
  const floatx4 zero = {0.f, 0.f, 0.f, 0.f};

  // K B-fragments (j fixed per wave) — loaded once
  short8 bk0 = *(const short8*)&k_t[(bn * 2048 + j0 + lr) * 32 + lk];
  short8 bk1 = *(const short8*)&k_t[(bn * 2048 + j0 + 16 + lr) * 32 + lk];

  floatx4 acc[2][2] = {{zero, zero}, {zero, zero}};
  const int pcol = (lane >> 4) * 4;

  for (int c0 = 0; c0 < 2048; c0 += 32) {
    short8 aq0 = *(const short8*)&q_t[(bn * 2048 + c0 + lr) * 32 + lk];
    short8 aq1 = *(const short8*)&q_t[(bn * 2048 + c0 + 16 + lr) * 32 + lk];
    floatx4 s00 = __builtin_amdgcn_mfma_f32_16x16x32_bf16(aq0, bk0, zero, 0, 0, 0);
    floatx4 s01 = __builtin_amdgcn_mfma_f32_16x16x32_bf16(aq0, bk1, zero, 0, 0, 0);
    floatx4 s10 = __builtin_amdgcn_mfma_f32_16x16x32_bf16(aq1, bk0, zero, 0, 0, 0);
    floatx4 s11 = __builtin_amdgcn_mfma_f32_16x16x32_bf16(aq1, bk1, zero, 0, 0, 0);

    // P = exp(S); write P^T[j][c] (per-wave private; same-wave RAW, no barrier)
    {
      uint2 w00 = {pack_bf16_2(__expf(s00[0]), __expf(s00[1])),
                   pack_bf16_2(__expf(s00[2]), __expf(s00[3]))};
      *(uint2*)&pt[wave][lr][pcol] = w00;                 // m=0, nt=0
      uint2 w01 = {pack_bf16_2(__expf(s01[0]), __expf(s01[1])),
                   pack_bf16_2(__expf(s01[2]), __expf(s01[3]))};
      *(uint2*)&pt[wave][16 + lr][pcol] = w01;            // m=0, nt=1
      uint2 w10 = {pack_bf16_2(__expf(s10[0]), __expf(s10[1])),
                   pack_bf16_2(__expf(s10[2]), __expf(s10[3]))};
      *(uint2*)&pt[wave][lr][16 + pcol] = w10;            // m=1, nt=0
      uint2 w11 = {pack_bf16_2(__expf(s11[0]), __expf(s11[1])),
                   pack_bf16_2(__expf(s11[2]), __expf(s11[3]))};
      *(uint2*)&pt[wave][16 + lr][16 + pcol] = w11;       // m=1, nt=1
    }

    short8 av0 = *(const short8*)&vz[(bh * 32 + lr) * HW + nn * 2048 + c0 + lk];
    short8 av1 = *(const short8*)&vz[(bh * 32 + 16 + lr) * HW + nn * 2048 + c0 + lk];
    short8 bp0 = *(const short8*)&pt[wave][lr][lk];
    short8 bp1 = *(const short8*)&pt[wave][16 + lr][lk];

    acc[0][0] = __builtin_amdgcn_mfma_f32_16x16x32_bf16(av0, bp0, acc[0][0], 0, 0, 0);
    acc[0][1] = __builtin_amdgcn_mfma_f32_16x16x32_bf16(av0, bp1, acc[0][1], 0, 0, 0);
    acc[1][0] = __builtin_amdgcn_mfma_f32_16x16x32_bf16(av1, bp0, acc[1][0], 0, 0, 0);
    acc[1][1] = __builtin_amdgcn_mfma_f32_16x16x32_bf16(av1, bp1, acc[1][1], 0, 0, 0);
  }

  #pragma unroll
  for (int m = 0; m < 2; ++m)
    #pragma unroll
    for (int nt = 0; nt < 2; ++nt)
      #pragma unroll
      for (int r = 0; r < 4; ++r)
        attn_out[(bh * 32 + m * 16 + (lane >> 4) * 4 + r) * HW +
                 nn * 2048 + j0 + nt * 16 + lr] = acc[m][nt][r];
}

// ---------------------------------------------------------------------------
// K4a: per-channel mean of attn_out -> s[128]
// ---------------------------------------------------------------------------
__global__ __launch_bounds__(256) void row_mean(
    const float* __restrict__ out, float* __restrict__ s) {
  const int ch = blockIdx.x;
  float sum = 0;
  const float4* row = (const float4*)(out + ch * HW);
  for (int p = threadIdx.x; p < HW / 4; p += 256) {
    float4 v = row[p];
    sum += (v.x + v.y) + (v.z + v.w);
  }
  __shared__ float red[256];
  red[threadIdx.x] = sum;
  __syncthreads();
  for (int st = 128; st > 0; st >>= 1) {
    if (threadIdx.x < st) red[threadIdx.x] += red[threadIdx.x + st];
    __syncthreads();
  }
  if (threadIdx.x == 0) s[ch] = red[0] * (1.f / HW);
}

// ---------------------------------------------------------------------------
// K4b: SE MLP -> gate g folded into out_w -> w_g
// ---------------------------------------------------------------------------
__global__ __launch_bounds__(128) void se_mlp(
    const float* __restrict__ s, const float* __restrict__ w1,
    const float* __restrict__ b1, const float* __restrict__ w2,
    const float* __restrict__ b2, const float* __restrict__ out_w,
    float* __restrict__ w_g) {
  __shared__ float s_sh[128], s1_sh[32], g_sh[128];
  const int t = threadIdx.x;
  s_sh[t] = s[t];
  __syncthreads();
  if (t < 32) {
    float a = b1[t];
    for (int c = 0; c < 128; ++c) a += w1[t * 128 + c] * s_sh[c];
    s1_sh[t] = a / (1.f + __expf(-a));
  }
  __syncthreads();
  {
    float a = b2[t];
    for (int i = 0; i < 32; ++i) a += w2[t * 32 + i] * s1_sh[i];
    g_sh[t] = 1.f / (1.f + __expf(-a));
  }
  __syncthreads();
  for (int o = 0; o < 128; ++o) w_g[o * 128 + t] = out_w[o * 128 + t] * g_sh[t];
}

// ---------------------------------------------------------------------------
// GroupNorm
// ---------------------------------------------------------------------------
__global__ __launch_bounds__(256) void gn_partial(
    const float* __restrict__ y, float* __restrict__ part) {
  const int g = blockIdx.x, bk = blockIdx.y;
  float s = 0, ss = 0;
  const float4* base = (const float4*)(y + g * 16 * HW + bk * 8192);
  for (int i = threadIdx.x; i < 2048; i += 256) {
    float4 v = base[i];
    s += (v.x + v.y) + (v.z + v.w);
    ss += (v.x * v.x + v.y * v.y) + (v.z * v.z + v.w * v.w);
  }
  __shared__ float r1[256], r2[256];
  r1[threadIdx.x] = s; r2[threadIdx.x] = ss;
  __syncthreads();
  for (int st = 128; st > 0; st >>= 1) {
    if (threadIdx.x < st) {
      r1[threadIdx.x] += r1[threadIdx.x + st];
      r2[threadIdx.x] += r2[threadIdx.x + st];
    }
    __syncthreads();
  }
  if (threadIdx.x == 0) {
    part[(g * 32 + bk) * 2 + 0] = r1[0];
    part[(g * 32 + bk) * 2 + 1] = r2[0];
  }
}

__global__ void gn_finalize(const float* __restrict__ part, float* __restrict__ stat) {
  const int g = threadIdx.x;
  if (g >= 8) return;
  float s = 0, ss = 0;
  for (int i = 0; i < 32; ++i) {
    s += part[(g * 32 + i) * 2 + 0];
    ss += part[(g * 32 + i) * 2 + 1];
  }
  const float inv_n = 1.f / (16.f * HW);
  float mu = s * inv_n;
  float var = ss * inv_n - mu * mu;
  stat[g * 2 + 0] = mu;
  stat[g * 2 + 1] = rsqrtf(var + 1e-5f);
}

__global__ __launch_bounds__(256) void gn_apply(
    const float* __restrict__ y, const float* __restrict__ stat,
    const float* __restrict__ gn_w, const float* __restrict__ gn_b,
    float* __restrict__ outp) {
  const int i = (blockIdx.x * 256 + threadIdx.x) * 4;
  const int ch = i >> 14;
  const int g = ch >> 4;
  float mu = stat[g * 2], rs = stat[g * 2 + 1];
  float w = gn_w[ch] * rs;
  float b = gn_b[ch] - mu * w;
  float4 v = *(const float4*)&y[i];
  float4 r = {v.x * w + b, v.y * w + b, v.z * w + b, v.w * w + b};
  *(float4*)&outp[i] = r;
}

// ---------------------------------------------------------------------------
extern "C" void kernel_launch(void* const* d_in, const int* in_sizes, int n_in,
                              void* d_out, int out_size, void* d_ws, size_t ws_size,
                              hipStream_t stream) {
  const float* x     = (const float*)d_in[0];
  const float* w_qkv = (const float*)d_in[1];
  const float* se_w1 = (const float*)d_in[2];
  const float* se_b1 = (const float*)d_in[3];
  const float* se_w2 = (const float*)d_in[4];
  const float* se_b2 = (const float*)d_in[5];
  const float* out_w = (const float*)d_in[6];
  const float* out_b = (const float*)d_in[7];
  const float* gn_w  = (const float*)d_in[8];
  const float* gn_b  = (const float*)d_in[9];
  float* out = (float*)d_out;

  float* ws = (float*)d_ws;
  float* qkv      = ws;                       // 6291456 f
  float* zinv     = qkv + 6291456;            // 65536 f
  float* attn_out = zinv + 65536;             // 2097152 f
  float* se_s     = attn_out + 2097152;       // 128 f
  float* w_g      = se_s + 128;               // 16384 f
  float* ybuf     = w_g + 16384;              // 2097152 f
  float* part     = ybuf + 2097152;           // 512 f
  float* stat     = part + 512;               // 16 f
  unsigned short* q_t = (unsigned short*)(stat + 16);  // 2097152 bf16
  unsigned short* k_t = q_t + 2097152;                 // 2097152 bf16
  unsigned short* vz  = k_t + 2097152;                 // 2097152 bf16

  gemm_ox<<<dim3(6, 128), 256, 0, stream>>>(w_qkv, x, nullptr, qkv);
  transpose_qk<<<dim3(8, 32, 2), 256, 0, stream>>>(qkv, q_t, k_t);
  attn_stats_mfma<<<dim3(8, 32), 512, 0, stream>>>(q_t, k_t, zinv);
  vz_cast<<<2048, 256, 0, stream>>>(qkv, zinv, vz);
  attn_apply_mfma<<<dim3(8, 32), 512, 0, stream>>>(q_t, k_t, vz, attn_out);
  row_mean<<<128, 256, 0, stream>>>(attn_out, se_s);
  se_mlp<<<1, 128, 0, stream>>>(se_s, se_w1, se_b1, se_w2, se_b2, out_w, w_g);
  gemm_ox<<<dim3(2, 128), 256, 0, stream>>>(w_g, attn_out, out_b, ybuf);
  gn_partial<<<dim3(8, 32), 256, 0, stream>>>(ybuf, part);
  gn_finalize<<<1, 64, 0, stream>>>(part, stat);
  gn_apply<<<2048, 256, 0, stream>>>(ybuf, stat, gn_w, gn_b, out);
}